// Round 1
// baseline (436.505 us; speedup 1.0000x reference)
//
#include <hip/hip_runtime.h>

// SoftDTW: B=64, N=512, M=512, DIM=64, GAMMA=1.0, BANDWIDTH=0, BIG=1e10
constexpr int Bc   = 64;
constexpr int Nc   = 512;
constexpr int Mc   = 512;
constexpr int DIMc = 64;
constexpr float BIGc = 1e10f;
constexpr int CELLS = Nc * Mc;           // compact diag storage per batch (1 MiB)

// offset of anti-diagonal dg (= n+m, dg in [0, N+M-2]) in compact storage
__device__ __forceinline__ int diag_off(int dg) {
    if (dg < Mc) return dg * (dg + 1) / 2;           // widths 1..512
    int e = dg - Mc;                                  // widths 511..1
    return Mc * (Mc + 1) / 2 + e * (Nc - 1) - e * (e - 1) / 2;
}
__device__ __forceinline__ int diag_nmin(int dg) {
    return (dg > Mc - 1) ? (dg - (Mc - 1)) : 0;
}

// ---------------- Kernel A: D[b,n,m] = ||X[b,n]-Y[b,m]||^2, diag-major compact ----
__global__ __launch_bounds__(256)
void compute_D_diag(const float* __restrict__ X, const float* __restrict__ Y,
                    float* __restrict__ Dc)
{
    const int b   = blockIdx.x;
    const int nt  = blockIdx.y;          // 64-row n tile
    const int tid = threadIdx.x;
    const int ty  = tid >> 4, tx = tid & 15;

    __shared__ float Xs[DIMc][68];       // transposed, padded (float4-aligned rows)
    __shared__ float Ys[DIMc][68];

    const float* Xb = X + ((size_t)b * Nc + (size_t)nt * 64) * DIMc;
    const float* Yb = Y + (size_t)b * Mc * DIMc;
    float*       Db = Dc + (size_t)b * CELLS;

    for (int c = tid; c < 64 * DIMc; c += 256) {
        Xs[c & 63][c >> 6] = Xb[c];      // c = n*64 + k -> Xs[k][n]
    }

    for (int mt = 0; mt < Mc / 64; ++mt) {
        __syncthreads();                 // Xs visible / prev Ys reads done
        for (int c = tid; c < 64 * DIMc; c += 256) {
            Ys[c & 63][c >> 6] = Yb[(size_t)mt * 64 * DIMc + c];
        }
        __syncthreads();

        float acc[4][4];
        #pragma unroll
        for (int r = 0; r < 4; ++r)
            #pragma unroll
            for (int cc = 0; cc < 4; ++cc) acc[r][cc] = 0.f;

        #pragma unroll 8
        for (int k = 0; k < DIMc; ++k) {
            float4 xv = *reinterpret_cast<const float4*>(&Xs[k][ty * 4]);
            float4 yv = *reinterpret_cast<const float4*>(&Ys[k][tx * 4]);
            float xr[4] = {xv.x, xv.y, xv.z, xv.w};
            float yr[4] = {yv.x, yv.y, yv.z, yv.w};
            #pragma unroll
            for (int r = 0; r < 4; ++r)
                #pragma unroll
                for (int cc = 0; cc < 4; ++cc) {
                    float d = xr[r] - yr[cc];
                    acc[r][cc] = fmaf(d, d, acc[r][cc]);
                }
        }

        #pragma unroll
        for (int r = 0; r < 4; ++r) {
            const int n = nt * 64 + ty * 4 + r;
            #pragma unroll
            for (int cc = 0; cc < 4; ++cc) {
                const int m  = mt * 64 + tx * 4 + cc;
                const int dg = n + m;
                Db[diag_off(dg) + (n - diag_nmin(dg))] = acc[r][cc];
            }
        }
    }
}

// ---------------- Kernel B: anti-diagonal soft-DTW recurrence ----------------
template<bool PRECOMP>
__global__ __launch_bounds__(512)
void softdtw_kernel(const float* __restrict__ Dc,
                    const float* __restrict__ X, const float* __restrict__ Y,
                    const int* __restrict__ lengths, float* __restrict__ out)
{
    const int b = blockIdx.x;
    const int t = threadIdx.x;           // row i = t+1, fixed per thread
    const int i = t + 1;
    const int L = lengths[b];

    __shared__ float diag[3][Nc + 1];    // rotating diagonals, index by row i

    for (int c = t; c <= Nc; c += 512) {
        diag[0][c] = (c == 0) ? 0.f : BIGc;   // diag k=0: R[0][0]=0
        diag[1][c] = BIGc;                    // diag k=1
    }

    float xr[DIMc];
    const float* Yb = nullptr;
    if (!PRECOMP) {
        const float* Xrow = X + ((size_t)b * Nc + t) * DIMc;
        #pragma unroll
        for (int d = 0; d < DIMc; d += 4) {
            float4 v = *reinterpret_cast<const float4*>(Xrow + d);
            xr[d] = v.x; xr[d+1] = v.y; xr[d+2] = v.z; xr[d+3] = v.w;
        }
        Yb = Y + (size_t)b * Mc * DIMc;
    }
    const float* Db = PRECOMP ? (Dc + (size_t)b * CELLS) : nullptr;

    __syncthreads();

    float Dnext = 0.f;
    if (PRECOMP && i == 1) Dnext = Db[0];     // cell (0,0) used at k=2
    float result = BIGc;

    int cur = 2, p1 = 1, p2 = 0;              // buffer indices (k%3 rotation)
    for (int k = 2; k <= Nc + Mc; ++k) {
        const int j = k - i;
        const bool valid = (j >= 1) && (j <= Mc) && (i <= L);

        float Dval;
        if (PRECOMP) {
            Dval = Dnext;
            const int j2 = k + 1 - i;          // prefetch diag k+1 (dg = k-1)
            if (j2 >= 1 && j2 <= Mc && k + 1 <= Nc + Mc) {
                const int dg = k - 1;
                Dnext = Db[diag_off(dg) + (i - 1 - diag_nmin(dg))];
            }
        } else {
            Dval = 0.f;
            if (valid) {
                const float* Yrow = Yb + (size_t)(j - 1) * DIMc;
                float s = 0.f;
                #pragma unroll
                for (int d = 0; d < DIMc; d += 4) {
                    float4 v = *reinterpret_cast<const float4*>(Yrow + d);
                    float d0 = xr[d]   - v.x, d1 = xr[d+1] - v.y;
                    float d2 = xr[d+2] - v.z, d3 = xr[d+3] - v.w;
                    s = fmaf(d0, d0, s); s = fmaf(d1, d1, s);
                    s = fmaf(d2, d2, s); s = fmaf(d3, d3, s);
                }
                Dval = s;
            }
        }

        const float a2 = diag[p2][i - 1];      // R[i-1][j-1]
        const float a1 = diag[p1][i - 1];      // R[i-1][j]
        const float a0 = diag[p1][i];          // R[i][j-1]
        const float mn = fminf(a2, fminf(a1, a0));
        const float sm = mn - __logf(__expf(mn - a2) + __expf(mn - a1) + __expf(mn - a0));
        const float val = valid ? (Dval + sm) : BIGc;

        diag[cur][i] = val;
        if (t == 0) diag[cur][0] = BIGc;       // R[0][k] = BIG
        if (k == L + Mc && i == L) result = val;
        __syncthreads();

        const int tmp = p2; p2 = p1; p1 = cur; cur = tmp;
    }
    if (i == L) out[b] = result;
}

extern "C" void kernel_launch(void* const* d_in, const int* in_sizes, int n_in,
                              void* d_out, int out_size, void* d_ws, size_t ws_size,
                              hipStream_t stream) {
    const float* X = (const float*)d_in[0];
    const float* Y = (const float*)d_in[1];
    const int* lengths = (const int*)d_in[2];
    float* out = (float*)d_out;

    const size_t need = (size_t)Bc * CELLS * sizeof(float);   // 64 MiB
    if (ws_size >= need) {
        float* Dc = (float*)d_ws;
        compute_D_diag<<<dim3(Bc, Nc / 64), 256, 0, stream>>>(X, Y, Dc);
        softdtw_kernel<true><<<Bc, 512, 0, stream>>>(Dc, nullptr, nullptr, lengths, out);
    } else {
        softdtw_kernel<false><<<Bc, 512, 0, stream>>>(nullptr, X, Y, lengths, out);
    }
}

// Round 2
// 364.441 us; speedup vs baseline: 1.1977x; 1.1977x over previous
//
#include <hip/hip_runtime.h>

// SoftDTW: B=64, N=512, M=512, DIM=64, GAMMA=1.0, BANDWIDTH=0, BIG=1e10
constexpr int Bc   = 64;
constexpr int Nc   = 512;
constexpr int Mc   = 512;
constexpr int DIMc = 64;
constexpr float BIGc = 1e10f;
constexpr int CELLS = Nc * Mc;      // compact diag storage per batch (1 MiB)
constexpr int CHUNK = 32;           // steps between barriers in DTW kernel
constexpr int NW    = 8;            // waves per DTW block (512 threads)
constexpr int NCHUNKS = (Nc + Mc - 2 + CHUNK - 1) / CHUNK + NW - 1;  // 39

// offset of anti-diagonal dg (= n+m, dg in [0, N+M-2]) in compact storage
__device__ __forceinline__ int diag_off(int dg) {
    if (dg < Mc) return dg * (dg + 1) / 2;            // widths 1..512
    int e = dg - Mc;                                   // widths 511..1
    return Mc * (Mc + 1) / 2 + e * (Nc - 1) - e * (e - 1) / 2;
}
__device__ __forceinline__ int diag_nmin(int dg) {
    return (dg > Mc - 1) ? (dg - (Mc - 1)) : 0;
}

// clamped load of D[r][dg-r] from diag-major storage (garbage-safe for
// out-of-range (dg,r): clamps into the array, caller masks via `valid`)
__device__ __forceinline__ float loadD(const float* __restrict__ Db, int dg, int r) {
    dg = min(max(dg, 0), Nc + Mc - 2);
    const int lo = max(0, dg - (Mc - 1));
    const int hi = min(Nc - 1, dg);
    const int rc = min(max(r, lo), hi);
    return Db[diag_off(dg) + rc - lo];
}

// ---------------- Kernel A: D[b,n,m] = ||X[b,n]-Y[b,m]||^2, diag-major compact ----
__global__ __launch_bounds__(256)
void compute_D_diag(const float* __restrict__ X, const float* __restrict__ Y,
                    float* __restrict__ Dc)
{
    const int b   = blockIdx.x;
    const int nt  = blockIdx.y;          // 64-row n tile
    const int tid = threadIdx.x;
    const int ty  = tid >> 4, tx = tid & 15;

    __shared__ float Xs[DIMc][68];       // transposed, padded
    __shared__ float Ys[DIMc][68];
    __shared__ float Ct[64][66];         // output tile staging (66: bank-stride 1 on diags)

    const float* Xb = X + ((size_t)b * Nc + (size_t)nt * 64) * DIMc;
    const float* Yb = Y + (size_t)b * Mc * DIMc;
    float*       Db = Dc + (size_t)b * CELLS;
    const int n0 = nt * 64;

    for (int c = tid; c < 64 * DIMc; c += 256)
        Xs[c & 63][c >> 6] = Xb[c];      // Xs[dim][row]

    for (int mt = 0; mt < Mc / 64; ++mt) {
        __syncthreads();                 // Xs/Ys/Ct reuse fence
        for (int c = tid; c < 64 * DIMc; c += 256)
            Ys[c & 63][c >> 6] = Yb[(size_t)mt * 64 * DIMc + c];
        __syncthreads();

        float acc[4][4];
        #pragma unroll
        for (int r = 0; r < 4; ++r)
            #pragma unroll
            for (int cc = 0; cc < 4; ++cc) acc[r][cc] = 0.f;

        #pragma unroll 8
        for (int k = 0; k < DIMc; ++k) {
            float4 xv = *reinterpret_cast<const float4*>(&Xs[k][ty * 4]);
            float4 yv = *reinterpret_cast<const float4*>(&Ys[k][tx * 4]);
            float xr[4] = {xv.x, xv.y, xv.z, xv.w};
            float yr[4] = {yv.x, yv.y, yv.z, yv.w};
            #pragma unroll
            for (int r = 0; r < 4; ++r)
                #pragma unroll
                for (int cc = 0; cc < 4; ++cc) {
                    float d = xr[r] - yr[cc];
                    acc[r][cc] = fmaf(d, d, acc[r][cc]);
                }
        }

        // stage tile in LDS, then write 127 contiguous diagonal segments
        #pragma unroll
        for (int r = 0; r < 4; ++r)
            #pragma unroll
            for (int cc = 0; cc < 4; ++cc)
                Ct[ty * 4 + r][tx * 4 + cc] = acc[r][cc];
        __syncthreads();

        const int grp  = tid >> 6;       // 4 groups of 64 lanes
        const int lane = tid & 63;
        const int m0   = mt * 64;
        for (int d = grp; d < 127; d += 4) {
            const int tn_lo = max(0, d - 63);
            const int tn_hi = min(63, d);
            if (lane <= tn_hi - tn_lo) {
                const int tn = tn_lo + lane;
                const int dg = n0 + m0 + d;
                Db[diag_off(dg) + (n0 + tn) - diag_nmin(dg)] = Ct[tn][d - tn];
            }
        }
    }
}

// ---------------- Kernel B: wave-systolic soft-DTW recurrence ----------------
// thread t -> row i = t+1 (wave w owns rows 64w+1..64w+64). Intra-wave
// neighbor values via shfl_up; wave boundaries via LDS rings, waves skewed by
// one CHUNK so rings are written a full chunk before being read. One barrier
// per CHUNK steps.
__global__ __launch_bounds__(512)
void softdtw_systolic(const float* __restrict__ Dc, const int* __restrict__ lengths,
                      float* __restrict__ out)
{
    const int b    = blockIdx.x;
    const int t    = threadIdx.x;
    const int w    = t >> 6;
    const int lane = t & 63;
    const int i    = t + 1;            // my row (1-based)
    const int L    = lengths[b];
    const float* Db = Dc + (size_t)b * CELLS;

    __shared__ float ring[NW][128];    // ring[w]: row 64w values, read by wave w lane 0

    float own = BIGc;                  // R[i][j-1]   (my value at k-1)
    float nb1 = BIGc;                  // R[i-1][j]   (neighbor at k-1)
    float nb2 = BIGc;                  // R[i-1][j-1] (neighbor at k-2)
    if (w == 0 && lane == 0) nb2 = 0.f;   // R[0][0]
    float res = BIGc;

    // prefetch first window (k in [2, 2+CHUNK)) -> dg = 0..CHUNK-1
    float Dbuf[CHUNK];
    #pragma unroll
    for (int s = 0; s < CHUNK; ++s)
        Dbuf[s] = loadD(Db, s, i - 1);

    for (int c = 0; c < NCHUNKS; ++c) {
        const int k0 = 2 + CHUNK * (c - w);
        const bool active = (c >= w) && (k0 <= 64 * w + 64 + Mc);
        if (active) {
            #pragma unroll
            for (int s = 0; s < CHUNK; ++s) {
                const int k = k0 + s;
                const int j = k - i;
                // softmin over {nb2, nb1, own}
                const float mn = fminf(nb2, fminf(nb1, own));
                const float e  = __expf(mn - nb2) + __expf(mn - nb1) + __expf(mn - own);
                const float sm = mn - __logf(e);
                const bool valid = ((unsigned)(j - 1) < (unsigned)Mc) && (i <= L);
                const float v = valid ? (Dbuf[s] + sm) : BIGc;
                if (i == L && j == Mc) res = v;           // R[L][M]
                // refill this slot for the next window (k + CHUNK)
                Dbuf[s] = loadD(Db, k + CHUNK - 2, i - 1);
                // boundary row export (lane 63 -> ring below)
                if (lane == 63 && w < NW - 1) ring[w + 1][k & 127] = v;
                // neighbor propagation
                const float ringv = ring[w][k & 127];     // uniform addr, broadcast
                const float sh = __shfl_up(v, 1);
                nb2 = nb1;
                nb1 = (lane == 0) ? ((w == 0) ? BIGc : ringv) : sh;
                own = v;
            }
        }
        __syncthreads();               // publish ring chunk, drain D prefetch
    }
    if (i == L) out[b] = res;
}

// ---------------- Fallback (no workspace): fused on-the-fly D ----------------
__global__ __launch_bounds__(512)
void softdtw_fused(const float* __restrict__ X, const float* __restrict__ Y,
                   const int* __restrict__ lengths, float* __restrict__ out)
{
    const int b = blockIdx.x;
    const int t = threadIdx.x;
    const int i = t + 1;
    const int L = lengths[b];

    __shared__ float diag[3][Nc + 1];
    for (int c = t; c <= Nc; c += 512) {
        diag[0][c] = (c == 0) ? 0.f : BIGc;
        diag[1][c] = BIGc;
    }
    float xr[DIMc];
    const float* Xrow = X + ((size_t)b * Nc + t) * DIMc;
    #pragma unroll
    for (int d = 0; d < DIMc; d += 4) {
        float4 v = *reinterpret_cast<const float4*>(Xrow + d);
        xr[d] = v.x; xr[d+1] = v.y; xr[d+2] = v.z; xr[d+3] = v.w;
    }
    const float* Yb = Y + (size_t)b * Mc * DIMc;
    __syncthreads();

    float result = BIGc;
    int cur = 2, p1 = 1, p2 = 0;
    for (int k = 2; k <= Nc + Mc; ++k) {
        const int j = k - i;
        const bool valid = (j >= 1) && (j <= Mc) && (i <= L);
        float Dval = 0.f;
        if (valid) {
            const float* Yrow = Yb + (size_t)(j - 1) * DIMc;
            float s = 0.f;
            #pragma unroll
            for (int d = 0; d < DIMc; d += 4) {
                float4 v = *reinterpret_cast<const float4*>(Yrow + d);
                float d0 = xr[d] - v.x, d1 = xr[d+1] - v.y;
                float d2 = xr[d+2] - v.z, d3 = xr[d+3] - v.w;
                s = fmaf(d0,d0,s); s = fmaf(d1,d1,s); s = fmaf(d2,d2,s); s = fmaf(d3,d3,s);
            }
            Dval = s;
        }
        const float a2 = diag[p2][i-1], a1 = diag[p1][i-1], a0 = diag[p1][i];
        const float mn = fminf(a2, fminf(a1, a0));
        const float sm = mn - __logf(__expf(mn-a2) + __expf(mn-a1) + __expf(mn-a0));
        const float val = valid ? (Dval + sm) : BIGc;
        diag[cur][i] = val;
        if (t == 0) diag[cur][0] = BIGc;
        if (k == L + Mc && i == L) result = val;
        __syncthreads();
        const int tmp = p2; p2 = p1; p1 = cur; cur = tmp;
    }
    if (i == L) out[b] = result;
}

extern "C" void kernel_launch(void* const* d_in, const int* in_sizes, int n_in,
                              void* d_out, int out_size, void* d_ws, size_t ws_size,
                              hipStream_t stream) {
    const float* X = (const float*)d_in[0];
    const float* Y = (const float*)d_in[1];
    const int* lengths = (const int*)d_in[2];
    float* out = (float*)d_out;

    const size_t need = (size_t)Bc * CELLS * sizeof(float);   // 64 MiB
    if (ws_size >= need) {
        float* Dc = (float*)d_ws;
        compute_D_diag<<<dim3(Bc, Nc / 64), 256, 0, stream>>>(X, Y, Dc);
        softdtw_systolic<<<Bc, 512, 0, stream>>>(Dc, lengths, out);
    } else {
        softdtw_fused<<<Bc, 512, 0, stream>>>(X, Y, lengths, out);
    }
}

// Round 3
// 282.773 us; speedup vs baseline: 1.5437x; 1.2888x over previous
//
#include <hip/hip_runtime.h>

// SoftDTW: B=64, N=512, M=512, DIM=64, GAMMA=1.0, BANDWIDTH=0, BIG=1e10
constexpr int Bc   = 64;
constexpr int Nc   = 512;
constexpr int Mc   = 512;
constexpr int DIMc = 64;
constexpr float BIGc = 1e10f;
constexpr int CELLS = Nc * Mc;      // compact diag storage per batch (1 MiB)
constexpr int CHUNK = 32;           // steps between barriers in DTW kernel
constexpr int NW    = 8;            // waves per DTW block (512 threads)
constexpr int NCHUNKS = (Nc + Mc - 2 + CHUNK - 1) / CHUNK + NW - 1;  // 39

// offset of anti-diagonal dg (= n+m, dg in [0, N+M-2]) in compact storage
__device__ __forceinline__ int diag_off(int dg) {
    if (dg < Mc) return dg * (dg + 1) / 2;            // widths 1..512
    int e = dg - Mc;                                   // widths 511..1
    return Mc * (Mc + 1) / 2 + e * (Nc - 1) - e * (e - 1) / 2;
}
__device__ __forceinline__ int diag_nmin(int dg) {
    return (dg > Mc - 1) ? (dg - (Mc - 1)) : 0;
}

// lane i <- lane i-1 across the full 64-lane wave (VALU-speed); lane 0 <- old
__device__ __forceinline__ float dpp_wave_shr1(float v, float old) {
    int r = __builtin_amdgcn_update_dpp(
        __builtin_bit_cast(int, old), __builtin_bit_cast(int, v),
        0x138 /*wave_shr:1*/, 0xF, 0xF, false);
    return __builtin_bit_cast(float, r);
}
__device__ __forceinline__ float f4c(const float4 v, int c) {
    switch (c & 3) { case 0: return v.x; case 1: return v.y;
                     case 2: return v.z; default: return v.w; }
}

// ---------------- Kernel A: D[b,n,m] = ||X[b,n]-Y[b,m]||^2, diag-major compact ----
__global__ __launch_bounds__(256)
void compute_D_diag(const float* __restrict__ X, const float* __restrict__ Y,
                    float* __restrict__ Dc)
{
    const int b   = blockIdx.x;
    const int nt  = blockIdx.y;          // 64-row n tile
    const int tid = threadIdx.x;
    const int ty  = tid >> 4, tx = tid & 15;

    __shared__ float Xs[DIMc][68];       // transposed, padded
    __shared__ float Ys[DIMc][68];
    __shared__ float Ct[64][66];         // output tile staging

    const float* Xb = X + ((size_t)b * Nc + (size_t)nt * 64) * DIMc;
    const float* Yb = Y + (size_t)b * Mc * DIMc;
    float*       Db = Dc + (size_t)b * CELLS;
    const int n0 = nt * 64;

    for (int c = tid; c < 64 * DIMc; c += 256)
        Xs[c & 63][c >> 6] = Xb[c];      // Xs[dim][row]

    for (int mt = 0; mt < Mc / 64; ++mt) {
        __syncthreads();                 // Xs/Ys/Ct reuse fence
        for (int c = tid; c < 64 * DIMc; c += 256)
            Ys[c & 63][c >> 6] = Yb[(size_t)mt * 64 * DIMc + c];
        __syncthreads();

        float acc[4][4];
        #pragma unroll
        for (int r = 0; r < 4; ++r)
            #pragma unroll
            for (int cc = 0; cc < 4; ++cc) acc[r][cc] = 0.f;

        #pragma unroll 8
        for (int k = 0; k < DIMc; ++k) {
            float4 xv = *reinterpret_cast<const float4*>(&Xs[k][ty * 4]);
            float4 yv = *reinterpret_cast<const float4*>(&Ys[k][tx * 4]);
            float xr[4] = {xv.x, xv.y, xv.z, xv.w};
            float yr[4] = {yv.x, yv.y, yv.z, yv.w};
            #pragma unroll
            for (int r = 0; r < 4; ++r)
                #pragma unroll
                for (int cc = 0; cc < 4; ++cc) {
                    float d = xr[r] - yr[cc];
                    acc[r][cc] = fmaf(d, d, acc[r][cc]);
                }
        }

        #pragma unroll
        for (int r = 0; r < 4; ++r)
            #pragma unroll
            for (int cc = 0; cc < 4; ++cc)
                Ct[ty * 4 + r][tx * 4 + cc] = acc[r][cc];
        __syncthreads();

        const int grp  = tid >> 6;       // 4 groups of 64 lanes
        const int lane = tid & 63;
        const int m0   = mt * 64;
        for (int d = grp; d < 127; d += 4) {
            const int tn_lo = max(0, d - 63);
            const int tn_hi = min(63, d);
            if (lane <= tn_hi - tn_lo) {
                const int tn = tn_lo + lane;
                const int dg = n0 + m0 + d;
                Db[diag_off(dg) + (n0 + tn) - diag_nmin(dg)] = Ct[tn][d - tn];
            }
        }
    }
}

// ---------------- Kernel B: DPP wave-systolic soft-DTW recurrence ----------------
// thread t -> row i = t+1. Intra-wave neighbor via DPP wave_shr:1 (VALU-speed).
// Wave boundaries via LDS rings (slot (k-2)&127; 32-aligned windows, no wrap),
// prefetched as 8x ds_read_b128 per chunk. Raw s_barrier (lgkm-only drain) so
// D prefetch loads stay in flight across chunks.
__global__ __launch_bounds__(512)
void softdtw_systolic(const float* __restrict__ Dc, const int* __restrict__ lengths,
                      float* __restrict__ out)
{
    const int b    = blockIdx.x;
    const int t    = threadIdx.x;
    const int w    = t >> 6;
    const int lane = t & 63;
    const int i    = t + 1;            // my row (1-based)
    const int L    = lengths[b];
    const float* Db = Dc + (size_t)b * CELLS;

    __shared__ float ring[NW][128];    // ring[w]: row 64w values for wave w lane 0

    float own = BIGc;                  // R[i][j-1]
    float nb1 = BIGc;                  // R[i-1][j]
    float nb2 = BIGc;                  // R[i-1][j-1]
    if (w == 0 && lane == 0) nb2 = 0.f;   // R[0][0]
    float res = BIGc;

    // initial D window: k in [2,34) -> dg = s, addr = s(s+1)/2 + (i-1)
    float Dbuf[CHUNK];
    #pragma unroll
    for (int s = 0; s < CHUNK; ++s)
        Dbuf[s] = Db[s * (s + 1) / 2 + t];
    int dAddr = (32 * 33) / 2 + t;     // off(dg=32) + (i-1); first refill dg = 32
    int dgr   = 32;

    for (int c = 0; c < NCHUNKS; ++c) {
        const int k0    = 2 + CHUNK * (c - w);
        const int rbase = (CHUNK * (c - w)) & 127;     // 32-aligned, no wrap

        // prefetch ring window (uniform broadcast reads, off the chain)
        float4 rv[8];
        const float4* rp4 = reinterpret_cast<const float4*>(&ring[w][rbase]);
        #pragma unroll
        for (int q = 0; q < 8; ++q) rv[q] = rp4[q];

        const bool active = (c >= w) && (k0 <= 64 * w + 64 + Mc);
        if (active) {
            #pragma unroll
            for (int s = 0; s < CHUNK; ++s) {
                const int k = k0 + s;
                const int j = k - i;
                // softmin over {nb2, nb1, own} (pure VALU chain)
                const float mn = fminf(nb2, fminf(nb1, own));
                const float e  = __expf(mn - nb2) + __expf(mn - nb1) + __expf(mn - own);
                const float sm = mn - __logf(e);
                const bool valid = ((unsigned)(j - 1) < (unsigned)Mc) && (i <= L);
                const float v = valid ? (Dbuf[s] + sm) : BIGc;
                if (i == L && j == Mc) res = v;            // R[L][M]
                // refill slot s for window k+CHUNK (dg = dgr), incremental addr
                Dbuf[s] = Db[dAddr];
                dAddr += (dgr < Nc - 1) ? (dgr + 1)
                                        : ((Nc + Mc - 2 - dgr) > 0 ? (Nc + Mc - 2 - dgr) : 0);
                ++dgr;
                // boundary export (lane 63 -> wave below)
                if (lane == 63 && w < NW - 1) ring[w + 1][rbase + s] = v;
                // neighbor propagation: DPP shift, ring override for lane 0
                const float sh = dpp_wave_shr1(v, BIGc);
                nb2 = nb1;
                nb1 = (w > 0 && lane == 0) ? f4c(rv[s >> 2], s) : sh;
                own = v;
            }
        }
        asm volatile("s_waitcnt lgkmcnt(0)" ::: "memory");  // ring writes visible
        __builtin_amdgcn_s_barrier();                       // NO vmcnt drain
        asm volatile("" ::: "memory");
    }
    if (i == L) out[b] = res;
}

// ---------------- Fallback (no workspace): fused on-the-fly D ----------------
__global__ __launch_bounds__(512)
void softdtw_fused(const float* __restrict__ X, const float* __restrict__ Y,
                   const int* __restrict__ lengths, float* __restrict__ out)
{
    const int b = blockIdx.x;
    const int t = threadIdx.x;
    const int i = t + 1;
    const int L = lengths[b];

    __shared__ float diag[3][Nc + 1];
    for (int c = t; c <= Nc; c += 512) {
        diag[0][c] = (c == 0) ? 0.f : BIGc;
        diag[1][c] = BIGc;
    }
    float xr[DIMc];
    const float* Xrow = X + ((size_t)b * Nc + t) * DIMc;
    #pragma unroll
    for (int d = 0; d < DIMc; d += 4) {
        float4 v = *reinterpret_cast<const float4*>(Xrow + d);
        xr[d] = v.x; xr[d+1] = v.y; xr[d+2] = v.z; xr[d+3] = v.w;
    }
    const float* Yb = Y + (size_t)b * Mc * DIMc;
    __syncthreads();

    float result = BIGc;
    int cur = 2, p1 = 1, p2 = 0;
    for (int k = 2; k <= Nc + Mc; ++k) {
        const int j = k - i;
        const bool valid = (j >= 1) && (j <= Mc) && (i <= L);
        float Dval = 0.f;
        if (valid) {
            const float* Yrow = Yb + (size_t)(j - 1) * DIMc;
            float s = 0.f;
            #pragma unroll
            for (int d = 0; d < DIMc; d += 4) {
                float4 v = *reinterpret_cast<const float4*>(Yrow + d);
                float d0 = xr[d] - v.x, d1 = xr[d+1] - v.y;
                float d2 = xr[d+2] - v.z, d3 = xr[d+3] - v.w;
                s = fmaf(d0,d0,s); s = fmaf(d1,d1,s); s = fmaf(d2,d2,s); s = fmaf(d3,d3,s);
            }
            Dval = s;
        }
        const float a2 = diag[p2][i-1], a1 = diag[p1][i-1], a0 = diag[p1][i];
        const float mn = fminf(a2, fminf(a1, a0));
        const float sm = mn - __logf(__expf(mn-a2) + __expf(mn-a1) + __expf(mn-a0));
        const float val = valid ? (Dval + sm) : BIGc;
        diag[cur][i] = val;
        if (t == 0) diag[cur][0] = BIGc;
        if (k == L + Mc && i == L) result = val;
        __syncthreads();
        const int tmp = p2; p2 = p1; p1 = cur; cur = tmp;
    }
    if (i == L) out[b] = result;
}

extern "C" void kernel_launch(void* const* d_in, const int* in_sizes, int n_in,
                              void* d_out, int out_size, void* d_ws, size_t ws_size,
                              hipStream_t stream) {
    const float* X = (const float*)d_in[0];
    const float* Y = (const float*)d_in[1];
    const int* lengths = (const int*)d_in[2];
    float* out = (float*)d_out;

    const size_t need = (size_t)Bc * CELLS * sizeof(float);   // 64 MiB
    if (ws_size >= need) {
        float* Dc = (float*)d_ws;
        compute_D_diag<<<dim3(Bc, Nc / 64), 256, 0, stream>>>(X, Y, Dc);
        softdtw_systolic<<<Bc, 512, 0, stream>>>(Dc, lengths, out);
    } else {
        softdtw_fused<<<Bc, 512, 0, stream>>>(X, Y, lengths, out);
    }
}